// Round 3
// baseline (699.356 us; speedup 1.0000x reference)
//
#include <hip/hip_runtime.h>
#include <hip/hip_bf16.h>
#include <cstdint>

#define K_DIM 768
#define M_DIM 3072
#define BS_TOTAL 16384  // B * S
#define BK 32
#define KT 24           // K_DIM / BK

typedef __attribute__((ext_vector_type(4))) float f32x4;
typedef __attribute__((ext_vector_type(8))) short bf16x8;
typedef __attribute__((ext_vector_type(4))) unsigned short u16x4;
typedef __attribute__((ext_vector_type(4))) float fv4;

typedef unsigned int u32_g __attribute__((address_space(1)));
typedef unsigned int u32_l __attribute__((address_space(3)));

static __device__ __forceinline__ void async_load16(const void* g, void* l) {
    __builtin_amdgcn_global_load_lds((const u32_g*)g, (u32_l*)l, 16, 0, 0);
}

#define BAR() __builtin_amdgcn_s_barrier()
#define SCHEDB() __builtin_amdgcn_sched_barrier(0)

static __device__ __forceinline__ unsigned short f2bf(float f) {
    unsigned u = __builtin_bit_cast(unsigned, f);
    u += 0x7fffu + ((u >> 16) & 1u);   // RNE
    return (unsigned short)(u >> 16);
}

__global__ void densify_kernel(const float* __restrict__ values,
                               const int* __restrict__ row_offsets,
                               const int* __restrict__ column_indices,
                               unsigned short* __restrict__ Wb) {
    const int r = blockIdx.x;
    const int t = threadIdx.x;
    unsigned int* wrow32 = (unsigned int*)(Wb + (size_t)r * K_DIM);
    for (int i = t; i < K_DIM / 2; i += 256) wrow32[i] = 0u;
    __syncthreads();
    const int start = row_offsets[r], end = row_offsets[r + 1];
    unsigned short* wrow = Wb + (size_t)r * K_DIM;
    for (int i = start + t; i < end; i += 256)
        wrow[column_indices[i]] = f2bf(values[i]);
}

__global__ void convert_x_kernel(const float* __restrict__ x,
                                 unsigned short* __restrict__ xb, int n4) {
    int i = blockIdx.x * 256 + threadIdx.x;
    if (i < n4) {
        fv4 v = ((const fv4*)x)[i];
        u16x4 o;
        o[0] = f2bf(v[0]); o[1] = f2bf(v[1]); o[2] = f2bf(v[2]); o[3] = f2bf(v[3]);
        ((u16x4*)xb)[i] = o;
    }
}

// ---- 256x256 tile, BK=32, 8 waves (2Mx4N), 4-phase, 64 KiB LDS -> 2 blocks/CU ----
// Row = 32 bf16 = 64 B = 4 x 16B blocks. Swizzle: blk ^= (row>>1)&3 -> 2-way banks.
// LDS dest linear u*16 (rule 21); XOR applied on global source + ds_read addr.

#define STAGE_A(buf, t)                                                         \
    { _Pragma("unroll") for (int c = 0; c < 2; ++c) {                           \
        const int u = c * 512 + tid;                                            \
        const int row = u >> 2;                                                 \
        const int gs = (u & 3) ^ ((row >> 1) & 3);                              \
        async_load16(X + (size_t)(row0 + row) * K_DIM + (t) * BK + gs * 8,      \
                     &sm[buf][0][(size_t)u * 8]); } }

#define STAGE_B(buf, t)                                                         \
    { _Pragma("unroll") for (int c = 0; c < 2; ++c) {                           \
        const int u = c * 512 + tid;                                            \
        const int row = u >> 2;                                                 \
        const int gs = (u & 3) ^ ((row >> 1) & 3);                              \
        async_load16(W + (size_t)(col0 + row) * K_DIM + (t) * BK + gs * 8,      \
                     &sm[buf][1][(size_t)u * 8]); } }

#define LDA(buf, mh)                                                            \
    { _Pragma("unroll") for (int mi = 0; mi < 4; ++mi) {                        \
        const int row = wm * 128 + (mh) * 64 + mi * 16 + fr;                    \
        const int blk = kq ^ ((row >> 1) & 3);                                  \
        aq[mi] = *(const bf16x8*)&sm[buf][0][row * BK + blk * 8]; } }

#define LDB(buf, nh, breg)                                                      \
    { _Pragma("unroll") for (int ni = 0; ni < 2; ++ni) {                        \
        const int row = wn * 64 + (nh) * 32 + ni * 16 + fr;                     \
        const int blk = kq ^ ((row >> 1) & 3);                                  \
        breg[ni] = *(const bf16x8*)&sm[buf][1][row * BK + blk * 8]; } }

#define MFMA8(mh, nh, breg)                                                     \
    { __builtin_amdgcn_s_setprio(1);                                            \
      _Pragma("unroll") for (int mi = 0; mi < 4; ++mi)                          \
      _Pragma("unroll") for (int ni = 0; ni < 2; ++ni)                          \
        acc[(mh)*4+mi][(nh)*2+ni] = __builtin_amdgcn_mfma_f32_16x16x32_bf16(    \
            aq[mi], breg[ni], acc[(mh)*4+mi][(nh)*2+ni], 0, 0, 0);              \
      __builtin_amdgcn_s_setprio(0); }

__global__ __launch_bounds__(512, 4) void gemm_kernel(
    const unsigned short* __restrict__ X,
    const unsigned short* __restrict__ W,
    const float* __restrict__ bias,
    float* __restrict__ out) {
    __shared__ __align__(16) unsigned short sm[2][2][256 * BK];  // 64 KiB

    // XCD-aware bijective swizzle: nwg = 768 (divisible by 8)
    const int nwg = gridDim.x;
    int bid = blockIdx.x;
    bid = (bid & 7) * (nwg >> 3) + (bid >> 3);
    const int bx = bid % (M_DIM / 256);   // 12 col tiles
    const int by = bid / (M_DIM / 256);   // 64 row tiles
    const int row0 = by * 256;
    const int col0 = bx * 256;

    const int tid  = threadIdx.x;
    const int lane = tid & 63;
    const int wave = tid >> 6;
    const int wm = wave >> 2;   // 0..1: A rows wm*128..+127
    const int wn = wave & 3;    // 0..3: B rows wn*64..+63
    const int fr = lane & 15;
    const int kq = lane >> 4;   // 0..3

    f32x4 acc[8][4] = {};
    bf16x8 aq[4], b0[2], b1[2];

    // prologue: tile0 A+B, tile1 B
    STAGE_A(0, 0);
    STAGE_B(0, 0);
    STAGE_B(1, 1);
    asm volatile("s_waitcnt vmcnt(2)" ::: "memory");  // tile0 done; B(1) in flight
    SCHEDB();
    BAR();

#pragma unroll 2
    for (int t = 0; t < KT; ++t) {
        const int buf = t & 1, nbuf = buf ^ 1;
        // P0: quadrant (0,0); prefetch A(t+1) -> nbuf
        LDA(buf, 0);
        LDB(buf, 0, b0);
        if (t + 1 < KT) STAGE_A(nbuf, t + 1);
        BAR();
        MFMA8(0, 0, b0);
        BAR();
        // P1: (0,1)
        LDB(buf, 1, b1);
        BAR();
        MFMA8(0, 1, b1);
        BAR();
        // P2: (1,1); prefetch B(t+2) -> buf (B reads of t finished at P1 barrier)
        LDA(buf, 1);
        if (t + 2 < KT) STAGE_B(buf, t + 2);
        BAR();
        MFMA8(1, 1, b1);
        BAR();
        // P3: (1,0) reuses b0; counted wait, never 0 in steady state
        MFMA8(1, 0, b0);
        if (t + 2 < KT)      { asm volatile("s_waitcnt vmcnt(2)" ::: "memory"); SCHEDB(); }
        else if (t + 1 < KT) { asm volatile("s_waitcnt vmcnt(0)" ::: "memory"); SCHEDB(); }
        BAR();
    }

    // epilogue: frag row = kq*4 + j, col = fr (m89-verified C/D layout)
    float bv[4];
#pragma unroll
    for (int ni = 0; ni < 4; ++ni) bv[ni] = bias[col0 + wn * 64 + ni * 16 + fr];

    const int orow0 = row0 + wm * 128 + kq * 4;
#pragma unroll
    for (int mi = 0; mi < 8; ++mi)
#pragma unroll
        for (int j = 0; j < 4; ++j) {
            float* op = out + (size_t)(orow0 + mi * 16 + j) * M_DIM + col0 + wn * 64 + fr;
#pragma unroll
            for (int ni = 0; ni < 4; ++ni)
                __builtin_nontemporal_store(acc[mi][ni][j] + bv[ni], op + ni * 16);
        }
}

extern "C" void kernel_launch(void* const* d_in, const int* in_sizes, int n_in,
                              void* d_out, int out_size, void* d_ws, size_t ws_size,
                              hipStream_t stream) {
    const float* values         = (const float*)d_in[0];
    const float* bias           = (const float*)d_in[1];
    const float* x              = (const float*)d_in[2];
    const int*   row_offsets    = (const int*)d_in[4];
    const int*   column_indices = (const int*)d_in[5];

    unsigned short* Wb = (unsigned short*)d_ws;
    unsigned short* Xb = (unsigned short*)((char*)d_ws + (size_t)M_DIM * K_DIM * 2);

    densify_kernel<<<M_DIM, 256, 0, stream>>>(values, row_offsets, column_indices, Wb);

    const int n4 = BS_TOTAL * K_DIM / 4;
    convert_x_kernel<<<(n4 + 255) / 256, 256, 0, stream>>>(x, Xb, n4);

    const int grid = (BS_TOTAL / 256) * (M_DIM / 256);  // 64 * 12 = 768
    gemm_kernel<<<grid, 512, 0, stream>>>(Xb, Wb, bias, (float*)d_out);
}

// Round 4
// 124.185 us; speedup vs baseline: 5.6316x; 5.6316x over previous
//
#include <hip/hip_runtime.h>
#include <hip/hip_bf16.h>
#include <cstdint>

#define K_DIM 768
#define M_DIM 3072
#define BS_TOTAL 16384  // B * S
#define BK 32
#define KT 24           // K_DIM / BK

typedef __attribute__((ext_vector_type(4))) float f32x4;
typedef __attribute__((ext_vector_type(8))) short bf16x8;
typedef __attribute__((ext_vector_type(4))) unsigned short u16x4;
typedef __attribute__((ext_vector_type(4))) float fv4;

typedef unsigned int u32_g __attribute__((address_space(1)));
typedef unsigned int u32_l __attribute__((address_space(3)));

static __device__ __forceinline__ void async_load16(const void* g, void* l) {
    __builtin_amdgcn_global_load_lds((const u32_g*)g, (u32_l*)l, 16, 0, 0);
}

#define BAR() __builtin_amdgcn_s_barrier()
#define SCHEDB() __builtin_amdgcn_sched_barrier(0)

static __device__ __forceinline__ unsigned short f2bf(float f) {
    unsigned u = __builtin_bit_cast(unsigned, f);
    u += 0x7fffu + ((u >> 16) & 1u);   // RNE
    return (unsigned short)(u >> 16);
}

__global__ void densify_kernel(const float* __restrict__ values,
                               const int* __restrict__ row_offsets,
                               const int* __restrict__ column_indices,
                               unsigned short* __restrict__ Wb) {
    const int r = blockIdx.x;
    const int t = threadIdx.x;
    unsigned int* wrow32 = (unsigned int*)(Wb + (size_t)r * K_DIM);
    for (int i = t; i < K_DIM / 2; i += 256) wrow32[i] = 0u;
    __syncthreads();
    const int start = row_offsets[r], end = row_offsets[r + 1];
    unsigned short* wrow = Wb + (size_t)r * K_DIM;
    for (int i = start + t; i < end; i += 256)
        wrow[column_indices[i]] = f2bf(values[i]);
}

__global__ void convert_x_kernel(const float* __restrict__ x,
                                 unsigned short* __restrict__ xb, int n4) {
    int i = blockIdx.x * 256 + threadIdx.x;
    if (i < n4) {
        fv4 v = ((const fv4*)x)[i];
        u16x4 o;
        o[0] = f2bf(v[0]); o[1] = f2bf(v[1]); o[2] = f2bf(v[2]); o[3] = f2bf(v[3]);
        ((u16x4*)xb)[i] = o;
    }
}

// ---- 128x128 tile, BK=32, 4 waves (2x2), dbuf 32 KiB LDS -> 4 blocks/CU ----
// Goal: occupancy so prologue/epilogue of one block hides under others' MFMA.
// Row = 32 bf16 = 64 B = 4 x 16B blocks. Swizzle: blk ^= (row>>1)&3 (measured
// 0 bank conflicts in round 3). LDS dest linear (rule 21); XOR on global source
// + on ds_read address (same involution both sides).

#define STAGE_A(buf, t)                                                         \
    { _Pragma("unroll") for (int c = 0; c < 2; ++c) {                           \
        const int u = c * 256 + tid;                                            \
        const int row = u >> 2;                                                 \
        const int gs = (u & 3) ^ ((row >> 1) & 3);                              \
        async_load16(X + (size_t)(row0 + row) * K_DIM + (t) * BK + gs * 8,      \
                     &sm[buf][0][(size_t)u * 8]); } }

#define STAGE_B(buf, t)                                                         \
    { _Pragma("unroll") for (int c = 0; c < 2; ++c) {                           \
        const int u = c * 256 + tid;                                            \
        const int row = u >> 2;                                                 \
        const int gs = (u & 3) ^ ((row >> 1) & 3);                              \
        async_load16(W + (size_t)(col0 + row) * K_DIM + (t) * BK + gs * 8,      \
                     &sm[buf][1][(size_t)u * 8]); } }

#define LDA(buf)                                                                \
    { _Pragma("unroll") for (int mi = 0; mi < 4; ++mi) {                        \
        const int row = wm * 64 + mi * 16 + fr;                                 \
        const int blk = kq ^ ((row >> 1) & 3);                                  \
        aq[mi] = *(const bf16x8*)&sm[buf][0][row * BK + blk * 8]; } }

#define LDB(buf)                                                                \
    { _Pragma("unroll") for (int ni = 0; ni < 4; ++ni) {                        \
        const int row = wn * 64 + ni * 16 + fr;                                 \
        const int blk = kq ^ ((row >> 1) & 3);                                  \
        bq[ni] = *(const bf16x8*)&sm[buf][1][row * BK + blk * 8]; } }

#define MFMA16()                                                                \
    { __builtin_amdgcn_s_setprio(1);                                            \
      _Pragma("unroll") for (int mi = 0; mi < 4; ++mi)                          \
      _Pragma("unroll") for (int ni = 0; ni < 4; ++ni)                          \
        acc[mi][ni] = __builtin_amdgcn_mfma_f32_16x16x32_bf16(                  \
            aq[mi], bq[ni], acc[mi][ni], 0, 0, 0);                              \
      __builtin_amdgcn_s_setprio(0); }

__global__ __launch_bounds__(256, 4) void gemm_kernel(
    const unsigned short* __restrict__ X,
    const unsigned short* __restrict__ W,
    const float* __restrict__ bias,
    float* __restrict__ out) {
    __shared__ __align__(16) unsigned short sm[2][2][128 * BK];  // 32 KiB

    // XCD-aware bijective swizzle: nwg = 3072 (divisible by 8)
    const int nwg = gridDim.x;
    int bid = blockIdx.x;
    bid = (bid & 7) * (nwg >> 3) + (bid >> 3);
    const int bx = bid % (M_DIM / 128);   // 24 col tiles
    const int by = bid / (M_DIM / 128);   // 128 row tiles
    const int row0 = by * 128;
    const int col0 = bx * 128;

    const int tid  = threadIdx.x;
    const int lane = tid & 63;
    const int wave = tid >> 6;
    const int wm = wave >> 1;   // 0..1: A rows wm*64..+63
    const int wn = wave & 1;    // 0..1: B rows wn*64..+63
    const int fr = lane & 15;
    const int kq = lane >> 4;   // 0..3

    f32x4 acc[4][4] = {};
    bf16x8 aq[4], bq[4];

    // prologue: tile 0
    STAGE_A(0, 0);
    STAGE_B(0, 0);
    asm volatile("s_waitcnt vmcnt(0)" ::: "memory");
    SCHEDB();
    BAR();

    for (int t = 0; t < KT; ++t) {
        const int buf = t & 1, nbuf = buf ^ 1;
        // ds_read this tile's fragments; issue next tile's staging
        LDA(buf);
        LDB(buf);
        if (t + 1 < KT) { STAGE_A(nbuf, t + 1); STAGE_B(nbuf, t + 1); }
        BAR();
        MFMA16();
        // drain staging before next tile reads nbuf; 4 resident blocks hide this
        asm volatile("s_waitcnt vmcnt(0)" ::: "memory");
        SCHEDB();
        BAR();
    }

    // epilogue: frag row = kq*4 + j, col = fr (m89-verified C/D layout)
    float bv[4];
#pragma unroll
    for (int ni = 0; ni < 4; ++ni) bv[ni] = bias[col0 + wn * 64 + ni * 16 + fr];

    const int orow0 = row0 + wm * 64 + kq * 4;
#pragma unroll
    for (int mi = 0; mi < 4; ++mi)
#pragma unroll
        for (int j = 0; j < 4; ++j) {
            float* op = out + (size_t)(orow0 + mi * 16 + j) * M_DIM + col0 + wn * 64 + fr;
#pragma unroll
            for (int ni = 0; ni < 4; ++ni)
                __builtin_nontemporal_store(acc[mi][ni][j] + bv[ni], op + ni * 16);
        }
}

extern "C" void kernel_launch(void* const* d_in, const int* in_sizes, int n_in,
                              void* d_out, int out_size, void* d_ws, size_t ws_size,
                              hipStream_t stream) {
    const float* values         = (const float*)d_in[0];
    const float* bias           = (const float*)d_in[1];
    const float* x              = (const float*)d_in[2];
    const int*   row_offsets    = (const int*)d_in[4];
    const int*   column_indices = (const int*)d_in[5];

    unsigned short* Wb = (unsigned short*)d_ws;
    unsigned short* Xb = (unsigned short*)((char*)d_ws + (size_t)M_DIM * K_DIM * 2);

    densify_kernel<<<M_DIM, 256, 0, stream>>>(values, row_offsets, column_indices, Wb);

    const int n4 = BS_TOTAL * K_DIM / 4;
    convert_x_kernel<<<(n4 + 255) / 256, 256, 0, stream>>>(x, Xb, n4);

    const int grid = (BS_TOTAL / 128) * (M_DIM / 128);  // 128 * 24 = 3072
    gemm_kernel<<<grid, 256, 0, stream>>>(Xb, Wb, bias, (float*)d_out);
}